// Round 5
// baseline (1227.543 us; speedup 1.0000x reference)
//
#include <hip/hip_runtime.h>
#include <math.h>

#define C        128
#define BLK      1024
#define WPB      (BLK / 64)   // 16 waves per block
#define MAXSLOT  24           // 48 rows staged per segment (bf16-packed, 2 VGPR/slot)

__device__ __forceinline__ float4 f4add(float4 a, float4 b) {
    float4 r; r.x = a.x + b.x; r.y = a.y + b.y; r.z = a.z + b.z; r.w = a.w + b.w; return r;
}
__device__ __forceinline__ float4 f4shfl_xor(float4 v, int m) {
    float4 r;
    r.x = __shfl_xor(v.x, m, 64);
    r.y = __shfl_xor(v.y, m, 64);
    r.z = __shfl_xor(v.z, m, 64);
    r.w = __shfl_xor(v.w, m, 64);
    return r;
}
__device__ __forceinline__ float fast_tanh(float v) {
    const float t = __expf(2.0f * v);
    return 1.0f - 2.0f / (t + 1.0f);
}
__device__ __forceinline__ float fast_sigmoid(float v) {
    return 1.0f / (1.0f + __expf(-v));
}

// float4 -> 2x u32, each holding two RNE-rounded bf16 values
__device__ __forceinline__ uint2 packf4(float4 v) {
    uint32_t x = __float_as_uint(v.x), y = __float_as_uint(v.y);
    uint32_t z = __float_as_uint(v.z), w = __float_as_uint(v.w);
    x = (x + 0x7FFFu + ((x >> 16) & 1u)) >> 16;
    y = (y + 0x7FFFu + ((y >> 16) & 1u)) & 0xFFFF0000u;
    z = (z + 0x7FFFu + ((z >> 16) & 1u)) >> 16;
    w = (w + 0x7FFFu + ((w >> 16) & 1u)) & 0xFFFF0000u;
    uint2 r; r.x = x | y; r.y = z | w; return r;
}
__device__ __forceinline__ float4 unpackf4(uint2 p) {
    float4 v;
    v.x = __uint_as_float(p.x << 16);
    v.y = __uint_as_float(p.x & 0xFFFF0000u);
    v.z = __uint_as_float(p.y << 16);
    v.w = __uint_as_float(p.y & 0xFFFF0000u);
    return v;
}
__device__ __forceinline__ float half_reduce(float d) {
    d += __shfl_xor(d, 16, 64);
    d += __shfl_xor(d,  8, 64);
    d += __shfl_xor(d,  4, 64);
    d += __shfl_xor(d,  2, 64);
    d += __shfl_xor(d,  1, 64);
    return d;
}

extern "C" __global__ __launch_bounds__(BLK, 4)   // 4 waves/EU -> VGPR <= 128, 16 waves/CU
void cba_bf16reg_kernel(const float* __restrict__ x,
                        const float* __restrict__ W,
                        const int* __restrict__ batch,
                        float* __restrict__ out,
                        int N, int B, int totalWaves)
{
    __shared__ float4 sW4[C * C / 4];   // 64 KB; 1 block/CU

    const int t    = threadIdx.x;
    const int lane = t & 63;
    const int q    = lane & 31;   // owns channels/cols 4q..4q+3
    const int h    = lane >> 5;   // half 0/1

    // ---- one-time: W into LDS ----
    const float4* Wg = (const float4*)W;
#pragma unroll
    for (int i = 0; i < (C * C / 4) / BLK; ++i)       // 4 iters
        sW4[t + i * BLK] = Wg[t + i * BLK];
    __syncthreads();

    const int gw = blockIdx.x * WPB + (t >> 6);       // global wave id, 0..4095

    // ---- chunk-contiguous segment assignment ----
    const int qn = B / totalWaves;
    const int r  = B % totalWaves;
    const int segStart = gw * qn + (gw < r ? gw : r);
    const int myCnt    = qn + (gw < r ? 1 : 0);       // ~12-13

    // ---- lane-parallel boundary search ----
    const int tl     = lane < myCnt ? lane : myCnt;
    const int target = segStart + tl;
    int lo = 0, hi = N;
    while (lo < hi) {
        int mid = (lo + hi) >> 1;
        if (batch[mid] < target) lo = mid + 1; else hi = mid;
    }
    const int bs = lo;
    const float4* x4 = (const float4*)x;

    for (int k = 0; k < myCnt; ++k) {
        const int b   = segStart + k;
        const int s   = __shfl(bs, k, 64);
        const int e   = __shfl(bs, k + 1, 64);
        const int cnt = e - s;

        // ======== stage + pass-1 fused: load fp32, sum fp32, keep bf16 copy ========
        uint2 rb[MAXSLOT];
        float4 a0 = make_float4(0.f,0.f,0.f,0.f), a1 = a0;
#pragma unroll
        for (int sl = 0; sl < MAXSLOT; ++sl) {
            const int row = s + 2 * sl + h;
            float4 v = make_float4(0.f, 0.f, 0.f, 0.f);
            if (row < e) v = x4[(size_t)row * 32 + q];
            if (sl & 1) a1 = f4add(a1, v); else a0 = f4add(a0, v);
            rb[sl] = packf4(v);
        }
        float4 acc = f4add(a0, a1);
        for (int i = s + 2 * MAXSLOT + h; i < e; i += 2)   // rows > 48 (rare, L2-hot later)
            acc = f4add(acc, x4[(size_t)i * 32 + q]);
        acc = f4add(acc, f4shfl_xor(acc, 32));
        const float inv = 1.0f / (float)(cnt > 0 ? cnt : 1);
        float4 mean;
        mean.x = acc.x * inv; mean.y = acc.y * inv;
        mean.z = acc.z * inv; mean.w = acc.w * inv;

        // ======== GEMM: c = tanh(mean @ W), split-K across halves ========
        float4 p = make_float4(0.f,0.f,0.f,0.f);
#pragma unroll
        for (int j = 0; j < 16; ++j) {
            const int src = (h << 4) + j;
            const float mx = __shfl(mean.x, src, 64);
            const float my = __shfl(mean.y, src, 64);
            const float mz = __shfl(mean.z, src, 64);
            const float mw = __shfl(mean.w, src, 64);
            const int k0 = (h << 6) + (j << 2);
            const float4 w0 = sW4[(k0 + 0) * 32 + q];
            const float4 w1 = sW4[(k0 + 1) * 32 + q];
            const float4 w2 = sW4[(k0 + 2) * 32 + q];
            const float4 w3 = sW4[(k0 + 3) * 32 + q];
            p.x = fmaf(mx, w0.x, p.x); p.y = fmaf(mx, w0.y, p.y);
            p.z = fmaf(mx, w0.z, p.z); p.w = fmaf(mx, w0.w, p.w);
            p.x = fmaf(my, w1.x, p.x); p.y = fmaf(my, w1.y, p.y);
            p.z = fmaf(my, w1.z, p.z); p.w = fmaf(my, w1.w, p.w);
            p.x = fmaf(mz, w2.x, p.x); p.y = fmaf(mz, w2.y, p.y);
            p.z = fmaf(mz, w2.z, p.z); p.w = fmaf(mz, w2.w, p.w);
            p.x = fmaf(mw, w3.x, p.x); p.y = fmaf(mw, w3.y, p.y);
            p.z = fmaf(mw, w3.z, p.z); p.w = fmaf(mw, w3.w, p.w);
        }
        p = f4add(p, f4shfl_xor(p, 32));
        float4 cv;
        cv.x = fast_tanh(p.x); cv.y = fast_tanh(p.y);
        cv.z = fast_tanh(p.z); cv.w = fast_tanh(p.w);

        // ======== pass 2: gates + h from bf16 registers ========
        float4 h0 = make_float4(0.f,0.f,0.f,0.f), h1 = h0;
#pragma unroll
        for (int g4 = 0; g4 < MAXSLOT / 4; ++g4) {         // 6 groups of 4 slots
            const float4 v0 = unpackf4(rb[4 * g4 + 0]);
            const float4 v1 = unpackf4(rb[4 * g4 + 1]);
            const float4 v2 = unpackf4(rb[4 * g4 + 2]);
            const float4 v3 = unpackf4(rb[4 * g4 + 3]);
            float d0 = v0.x*cv.x + v0.y*cv.y + v0.z*cv.z + v0.w*cv.w;
            float d1 = v1.x*cv.x + v1.y*cv.y + v1.z*cv.z + v1.w*cv.w;
            float d2 = v2.x*cv.x + v2.y*cv.y + v2.z*cv.z + v2.w*cv.w;
            float d3 = v3.x*cv.x + v3.y*cv.y + v3.z*cv.z + v3.w*cv.w;
            d0 += __shfl_xor(d0,16,64); d1 += __shfl_xor(d1,16,64);
            d2 += __shfl_xor(d2,16,64); d3 += __shfl_xor(d3,16,64);
            d0 += __shfl_xor(d0, 8,64); d1 += __shfl_xor(d1, 8,64);
            d2 += __shfl_xor(d2, 8,64); d3 += __shfl_xor(d3, 8,64);
            d0 += __shfl_xor(d0, 4,64); d1 += __shfl_xor(d1, 4,64);
            d2 += __shfl_xor(d2, 4,64); d3 += __shfl_xor(d3, 4,64);
            d0 += __shfl_xor(d0, 2,64); d1 += __shfl_xor(d1, 2,64);
            d2 += __shfl_xor(d2, 2,64); d3 += __shfl_xor(d3, 2,64);
            d0 += __shfl_xor(d0, 1,64); d1 += __shfl_xor(d1, 1,64);
            d2 += __shfl_xor(d2, 1,64); d3 += __shfl_xor(d3, 1,64);
            const float g0 = fast_sigmoid(d0);
            const float g1 = fast_sigmoid(d1);
            const float g2 = fast_sigmoid(d2);
            const float g3 = fast_sigmoid(d3);
            h0.x = fmaf(g0, v0.x, h0.x); h0.y = fmaf(g0, v0.y, h0.y);
            h0.z = fmaf(g0, v0.z, h0.z); h0.w = fmaf(g0, v0.w, h0.w);
            h1.x = fmaf(g1, v1.x, h1.x); h1.y = fmaf(g1, v1.y, h1.y);
            h1.z = fmaf(g1, v1.z, h1.z); h1.w = fmaf(g1, v1.w, h1.w);
            h0.x = fmaf(g2, v2.x, h0.x); h0.y = fmaf(g2, v2.y, h0.y);
            h0.z = fmaf(g2, v2.z, h0.z); h0.w = fmaf(g2, v2.w, h0.w);
            h1.x = fmaf(g3, v3.x, h1.x); h1.y = fmaf(g3, v3.y, h1.y);
            h1.z = fmaf(g3, v3.z, h1.z); h1.w = fmaf(g3, v3.w, h1.w);
        }
        // rows > 48: re-read from global (just touched in pass 1 -> L2-hot)
        for (int i = s + 2 * MAXSLOT + h; i < e; i += 2) {
            const float4 v = x4[(size_t)i * 32 + q];
            float d = v.x*cv.x + v.y*cv.y + v.z*cv.z + v.w*cv.w;
            d = half_reduce(d);
            const float g = fast_sigmoid(d);
            h0.x = fmaf(g, v.x, h0.x); h0.y = fmaf(g, v.y, h0.y);
            h0.z = fmaf(g, v.z, h0.z); h0.w = fmaf(g, v.w, h0.w);
        }
        float4 hacc = f4add(h0, h1);
        hacc = f4add(hacc, f4shfl_xor(hacc, 32));
        if (lane < 32)
            ((float4*)out)[(size_t)b * 32 + q] = hacc;
    }
}

extern "C" void kernel_launch(void* const* d_in, const int* in_sizes, int n_in,
                              void* d_out, int out_size, void* d_ws, size_t ws_size,
                              hipStream_t stream) {
    const float* x     = (const float*)d_in[0];
    const float* W     = (const float*)d_in[1];
    const int*   batch = (const int*)d_in[2];
    float*       out   = (float*)d_out;

    const int N = in_sizes[0] / C;   // 2,000,000
    const int B = out_size / C;      // 50,000

    const int grid       = 256;                 // 1 block/CU, 16 waves/CU resident
    const int totalWaves = grid * WPB;          // 4096 waves, ~12 contiguous segments each
    hipLaunchKernelGGL(cba_bf16reg_kernel, dim3(grid), dim3(BLK), 0, stream,
                       x, W, batch, out, N, B, totalWaves);
}

// Round 6
// 647.719 us; speedup vs baseline: 1.8952x; 1.8952x over previous
//
#include <hip/hip_runtime.h>
#include <math.h>

#define C        128
#define BLK      768
#define WPB      (BLK / 64)   // 12 waves per block
#define MAXSLOT  12           // 12 slots x 4 rows = 48 rows register-staged / segment

__device__ __forceinline__ float4 f4add(float4 a, float4 b) {
    float4 r; r.x = a.x + b.x; r.y = a.y + b.y; r.z = a.z + b.z; r.w = a.w + b.w; return r;
}
__device__ __forceinline__ float4 f4shfl_xor(float4 v, int m) {
    float4 r;
    r.x = __shfl_xor(v.x, m, 64);
    r.y = __shfl_xor(v.y, m, 64);
    r.z = __shfl_xor(v.z, m, 64);
    r.w = __shfl_xor(v.w, m, 64);
    return r;
}
__device__ __forceinline__ float fast_tanh(float v) {
    const float t = __expf(2.0f * v);
    return 1.0f - 2.0f / (t + 1.0f);
}
__device__ __forceinline__ float fast_sigmoid(float v) {
    return 1.0f / (1.0f + __expf(-v));
}
// sum across the 16 lanes of this row-group, result in every lane. Pure VALU (DPP),
// no DS pipe: row_ror 8/4/2/1 rotate-add tree.
__device__ __forceinline__ float row16_sum(float d) {
    d += __int_as_float(__builtin_amdgcn_update_dpp(0, __float_as_int(d), 0x128, 0xF, 0xF, true));
    d += __int_as_float(__builtin_amdgcn_update_dpp(0, __float_as_int(d), 0x124, 0xF, 0xF, true));
    d += __int_as_float(__builtin_amdgcn_update_dpp(0, __float_as_int(d), 0x122, 0xF, 0xF, true));
    d += __int_as_float(__builtin_amdgcn_update_dpp(0, __float_as_int(d), 0x121, 0xF, 0xF, true));
    return d;
}
__device__ __forceinline__ float dot8(float4 lo, float4 hi, float4 clo, float4 chi) {
    float a = lo.x * clo.x + lo.y * clo.y;
    float b = lo.z * clo.z + lo.w * clo.w;
    float c = hi.x * chi.x + hi.y * chi.y;
    float d = hi.z * chi.z + hi.w * chi.w;
    return (a + b) + (c + d);
}

extern "C" __global__ __launch_bounds__(BLK)
void cba_dpp_kernel(const float* __restrict__ x,
                    const float* __restrict__ W,
                    const int* __restrict__ batch,
                    float* __restrict__ out,
                    int N, int B, int totalWaves)
{
    __shared__ float4 sW4[C * C / 4];      // 64 KB fp32 W, row-major [k][col/4]
    __shared__ float4 sMean[WPB * 32];     // 6 KB: per-wave mean broadcast buffer

    const int t    = threadIdx.x;
    const int lane = t & 63;
    const int wid  = t >> 6;       // wave in block, 0..11
    const int rg   = lane >> 4;    // row-group 0..3 (rows), also split-K quarter
    const int c16  = lane & 15;    // owns channels c16*8 .. c16*8+7

    // ---- one-time: W into LDS ----
    const float4* Wg = (const float4*)W;
    for (int i = t; i < C * C / 4; i += BLK)
        sW4[i] = Wg[i];
    __syncthreads();

    const int gw = blockIdx.x * WPB + wid;            // global wave id

    // ---- chunk-contiguous segment assignment ----
    const int qn = B / totalWaves;
    const int r  = B % totalWaves;
    const int segStart = gw * qn + (gw < r ? gw : r);
    const int myCnt    = qn + (gw < r ? 1 : 0);       // ~16-17

    // ---- lane-parallel boundary search ----
    const int tl     = lane < myCnt ? lane : myCnt;
    const int target = segStart + tl;
    int lo_ = 0, hi_ = N;
    while (lo_ < hi_) {
        int mid = (lo_ + hi_) >> 1;
        if (batch[mid] < target) lo_ = mid + 1; else hi_ = mid;
    }
    const int bs = lo_;
    const float4* x4 = (const float4*)x;
    float4* mb = sMean + wid * 32;                    // this wave's 128-float scratch

    for (int k = 0; k < myCnt; ++k) {
        const int b   = segStart + k;
        const int s   = __shfl(bs, k, 64);
        const int e   = __shfl(bs, k + 1, 64);
        const int cnt = e - s;

        // ======== stage 48 rows (4/slot, one per row-group) + fused pass-1 sum ========
        float4 rbLo[MAXSLOT], rbHi[MAXSLOT];
        float4 alo = make_float4(0.f,0.f,0.f,0.f), ahi = alo;
#pragma unroll
        for (int sl = 0; sl < MAXSLOT; ++sl) {
            const int row = s + 4 * sl + rg;
            float4 vlo = make_float4(0.f,0.f,0.f,0.f), vhi = vlo;
            if (row < e) {
                vlo = x4[(size_t)row * 32 + c16 * 2];
                vhi = x4[(size_t)row * 32 + c16 * 2 + 1];
            }
            rbLo[sl] = vlo; rbHi[sl] = vhi;
            alo = f4add(alo, vlo); ahi = f4add(ahi, vhi);
        }
        // rare tail rows > 48: read + sum (re-read again in pass 2, L2-hot)
        for (int i = s + 4 * MAXSLOT + rg; i < e; i += 4) {
            alo = f4add(alo, x4[(size_t)i * 32 + c16 * 2]);
            ahi = f4add(ahi, x4[(size_t)i * 32 + c16 * 2 + 1]);
        }
        // cross-row-group reduce (only per segment, not per row)
        alo = f4add(alo, f4shfl_xor(alo, 16));
        alo = f4add(alo, f4shfl_xor(alo, 32));
        ahi = f4add(ahi, f4shfl_xor(ahi, 16));
        ahi = f4add(ahi, f4shfl_xor(ahi, 32));
        const float inv = 1.0f / (float)(cnt > 0 ? cnt : 1);
        float4 mlo, mhi;
        mlo.x = alo.x * inv; mlo.y = alo.y * inv; mlo.z = alo.z * inv; mlo.w = alo.w * inv;
        mhi.x = ahi.x * inv; mhi.y = ahi.y * inv; mhi.z = ahi.z * inv; mhi.w = ahi.w * inv;

        // ======== publish mean to per-wave LDS for the split-K GEMM broadcast ========
        if (lane < 16) {
            mb[2 * c16]     = mlo;
            mb[2 * c16 + 1] = mhi;
        }
        // (same-wave ds_write -> ds_read; compiler inserts lgkmcnt)

        // ======== GEMM: c = tanh(mean @ W); split-K: group rg covers k in [32rg,32rg+32) ========
        float4 plo = make_float4(0.f,0.f,0.f,0.f), phi = plo;
#pragma unroll
        for (int jq = 0; jq < 8; ++jq) {
            const float4 m4 = mb[rg * 8 + jq];        // mean[k..k+3], broadcast within group
            const int k0 = rg * 32 + jq * 4;
            const float4 w0l = sW4[(k0 + 0) * 32 + c16 * 2], w0h = sW4[(k0 + 0) * 32 + c16 * 2 + 1];
            const float4 w1l = sW4[(k0 + 1) * 32 + c16 * 2], w1h = sW4[(k0 + 1) * 32 + c16 * 2 + 1];
            const float4 w2l = sW4[(k0 + 2) * 32 + c16 * 2], w2h = sW4[(k0 + 2) * 32 + c16 * 2 + 1];
            const float4 w3l = sW4[(k0 + 3) * 32 + c16 * 2], w3h = sW4[(k0 + 3) * 32 + c16 * 2 + 1];
            plo.x = fmaf(m4.x, w0l.x, plo.x); plo.y = fmaf(m4.x, w0l.y, plo.y);
            plo.z = fmaf(m4.x, w0l.z, plo.z); plo.w = fmaf(m4.x, w0l.w, plo.w);
            phi.x = fmaf(m4.x, w0h.x, phi.x); phi.y = fmaf(m4.x, w0h.y, phi.y);
            phi.z = fmaf(m4.x, w0h.z, phi.z); phi.w = fmaf(m4.x, w0h.w, phi.w);
            plo.x = fmaf(m4.y, w1l.x, plo.x); plo.y = fmaf(m4.y, w1l.y, plo.y);
            plo.z = fmaf(m4.y, w1l.z, plo.z); plo.w = fmaf(m4.y, w1l.w, plo.w);
            phi.x = fmaf(m4.y, w1h.x, phi.x); phi.y = fmaf(m4.y, w1h.y, phi.y);
            phi.z = fmaf(m4.y, w1h.z, phi.z); phi.w = fmaf(m4.y, w1h.w, phi.w);
            plo.x = fmaf(m4.z, w2l.x, plo.x); plo.y = fmaf(m4.z, w2l.y, plo.y);
            plo.z = fmaf(m4.z, w2l.z, plo.z); plo.w = fmaf(m4.z, w2l.w, plo.w);
            phi.x = fmaf(m4.z, w2h.x, phi.x); phi.y = fmaf(m4.z, w2h.y, phi.y);
            phi.z = fmaf(m4.z, w2h.z, phi.z); phi.w = fmaf(m4.z, w2h.w, phi.w);
            plo.x = fmaf(m4.w, w3l.x, plo.x); plo.y = fmaf(m4.w, w3l.y, plo.y);
            plo.z = fmaf(m4.w, w3l.z, plo.z); plo.w = fmaf(m4.w, w3l.w, plo.w);
            phi.x = fmaf(m4.w, w3h.x, phi.x); phi.y = fmaf(m4.w, w3h.y, phi.y);
            phi.z = fmaf(m4.w, w3h.z, phi.z); phi.w = fmaf(m4.w, w3h.w, phi.w);
        }
        // combine the 4 K-quarters (per segment, cheap)
        plo = f4add(plo, f4shfl_xor(plo, 16));
        plo = f4add(plo, f4shfl_xor(plo, 32));
        phi = f4add(phi, f4shfl_xor(phi, 16));
        phi = f4add(phi, f4shfl_xor(phi, 32));
        float4 clo, chi;
        clo.x = fast_tanh(plo.x); clo.y = fast_tanh(plo.y);
        clo.z = fast_tanh(plo.z); clo.w = fast_tanh(plo.w);
        chi.x = fast_tanh(phi.x); chi.y = fast_tanh(phi.y);
        chi.z = fast_tanh(phi.z); chi.w = fast_tanh(phi.w);

        // ======== pass 2: gates + h, DPP-only row reduction, zero DS in the loop ========
        float4 hlo = make_float4(0.f,0.f,0.f,0.f), hhi = hlo;
#pragma unroll
        for (int sl = 0; sl < MAXSLOT; ++sl) {
            const float4 vlo = rbLo[sl], vhi = rbHi[sl];
            float d = dot8(vlo, vhi, clo, chi);
            d = row16_sum(d);                          // full dot across the 16-lane group
            const float g = fast_sigmoid(d);           // masked rows: v=0 -> g*0 = 0
            hlo.x = fmaf(g, vlo.x, hlo.x); hlo.y = fmaf(g, vlo.y, hlo.y);
            hlo.z = fmaf(g, vlo.z, hlo.z); hlo.w = fmaf(g, vlo.w, hlo.w);
            hhi.x = fmaf(g, vhi.x, hhi.x); hhi.y = fmaf(g, vhi.y, hhi.y);
            hhi.z = fmaf(g, vhi.z, hhi.z); hhi.w = fmaf(g, vhi.w, hhi.w);
        }
        // tail rows > 48: re-read (L2-hot from pass-1)
        for (int i = s + 4 * MAXSLOT + rg; i < e; i += 4) {
            const float4 vlo = x4[(size_t)i * 32 + c16 * 2];
            const float4 vhi = x4[(size_t)i * 32 + c16 * 2 + 1];
            float d = dot8(vlo, vhi, clo, chi);
            d = row16_sum(d);
            const float g = fast_sigmoid(d);
            hlo.x = fmaf(g, vlo.x, hlo.x); hlo.y = fmaf(g, vlo.y, hlo.y);
            hlo.z = fmaf(g, vlo.z, hlo.z); hlo.w = fmaf(g, vlo.w, hlo.w);
            hhi.x = fmaf(g, vhi.x, hhi.x); hhi.y = fmaf(g, vhi.y, hhi.y);
            hhi.z = fmaf(g, vhi.z, hhi.z); hhi.w = fmaf(g, vhi.w, hhi.w);
        }
        // cross-row-group combine + store
        hlo = f4add(hlo, f4shfl_xor(hlo, 16));
        hlo = f4add(hlo, f4shfl_xor(hlo, 32));
        hhi = f4add(hhi, f4shfl_xor(hhi, 16));
        hhi = f4add(hhi, f4shfl_xor(hhi, 32));
        if (lane < 16) {
            ((float4*)out)[(size_t)b * 32 + 2 * c16]     = hlo;
            ((float4*)out)[(size_t)b * 32 + 2 * c16 + 1] = hhi;
        }
    }
}

extern "C" void kernel_launch(void* const* d_in, const int* in_sizes, int n_in,
                              void* d_out, int out_size, void* d_ws, size_t ws_size,
                              hipStream_t stream) {
    const float* x     = (const float*)d_in[0];
    const float* W     = (const float*)d_in[1];
    const int*   batch = (const int*)d_in[2];
    float*       out   = (float*)d_out;

    const int N = in_sizes[0] / C;   // 2,000,000
    const int B = out_size / C;      // 50,000

    const int grid       = 256;                 // 1 block/CU, 12 waves/CU
    const int totalWaves = grid * WPB;          // 3072 waves, ~16 contiguous segments each
    hipLaunchKernelGGL(cba_dpp_kernel, dim3(grid), dim3(BLK), 0, stream,
                       x, W, batch, out, N, B, totalWaves);
}